// Round 8
// baseline (381.505 us; speedup 1.0000x reference)
//
#include <hip/hip_runtime.h>
#include <stdint.h>

#define N_NODES 100000
#define N_EDGES 1600000
#define NBLK_SCAN 391   // ceil(N_NODES/256)

typedef __attribute__((ext_vector_type(8))) short short8;
typedef __attribute__((ext_vector_type(4))) float float4v;

__device__ __forceinline__ unsigned short f32_to_bf16(float f) {
  uint32_t u = __float_as_uint(f);
  u += 0x7fffu + ((u >> 16) & 1u);   // RNE
  return (unsigned short)(u >> 16);
}
__device__ __forceinline__ float bf16_to_f32(unsigned short h) {
  return __uint_as_float(((uint32_t)h) << 16);
}
__device__ __forceinline__ unsigned pack2bf16(float a, float b) {
  return (unsigned)f32_to_bf16(a) | ((unsigned)f32_to_bf16(b) << 16);
}

// ---------------------------------------------------------------------------
// K_zero: deg=0, tilepack=0, tilectr=0; swizzle weight (tiles 0..49), root_w
// (tiles 50..51), and M[26][32] (tiles 52..53, zero-padded to 32) into the
// shared A/B fragment order: wbf[((t*4+q)*16+c)*8+j] = W[kk=q*8+j][col=c].
// M[k][fin] = sum_fo W_k[fin][fo]*att_w[32+fo] (k<25); M[25][fin] =
// sum_fo root_w[fin][fo]*att_w[fo].
// ---------------------------------------------------------------------------
__global__ __launch_bounds__(256) void k_zero(
    const float* __restrict__ weight, const float* __restrict__ root_w,
    const float* __restrict__ att_w,
    int* __restrict__ deg, unsigned short* __restrict__ wbf,
    unsigned long long* __restrict__ tilepack, int* __restrict__ tilectr) {
  int tid = threadIdx.x;
  int b = blockIdx.x;
  int i = b * 256 + tid;
  if (i < N_NODES) deg[i] = 0;
  if (i < NBLK_SCAN) tilepack[i] = 0ull;
  if (i == 0) *tilectr = 0;
  if (b < 100) {            // 25600 weight elements -> tiles 0..49
    int e = i;
    int km = e >> 10;
    int rem = e & 1023;
    int kk = rem >> 5;
    int fo = rem & 31;
    int t = km * 2 + (fo >> 4);
    int c = fo & 15;
    int q = kk >> 3, j = kk & 7;
    wbf[((t * 4 + q) * 16 + c) * 8 + j] = f32_to_bf16(weight[e]);
  } else if (b == 100) {    // 1024 root_w elements -> tiles 50,51
    for (int idx = tid; idx < 1024; idx += 256) {
      int kk = idx >> 5;
      int fo = idx & 31;
      int t = 50 + (fo >> 4);
      int c = fo & 15;
      int q = kk >> 3, j = kk & 7;
      wbf[((t * 4 + q) * 16 + c) * 8 + j] = f32_to_bf16(root_w[idx]);
    }
  } else if (b == 101) {    // M tiles 52,53 (cols 26..31 zero)
    for (int idx = tid; idx < 1024; idx += 256) {
      int cg = idx >> 5;    // 0..31
      int kk = idx & 31;    // fin
      float s = 0.f;
      if (cg < 25) {
        const float* wp = weight + (cg * 32 + kk) * 32;
#pragma unroll
        for (int fo = 0; fo < 32; fo++) s += wp[fo] * att_w[32 + fo];
      } else if (cg == 25) {
        const float* rp = root_w + kk * 32;
#pragma unroll
        for (int fo = 0; fo < 32; fo++) s += rp[fo] * att_w[fo];
      }
      int t = 52 + (cg >> 4);
      int c = cg & 15;
      int q = kk >> 3, j = kk & 7;
      wbf[((t * 4 + q) * 16 + c) * 8 + j] = f32_to_bf16(s);
    }
  }
}

// ---------------------------------------------------------------------------
// K1 (6250 blocks, 16 nodes each; 6250*256 == N_EDGES exactly):
//  - hist: rank[e] = atomicAdd(&deg[ei[e]],1)
//  - D[f,node] = mfma(W_frag as A, x_frag as B): lane holds 4 CONSECUTIVE
//    f-values of one node -> direct packed stores, NO LDS, NO barrier.
//    tiles 0..49 -> xw (8B dwordx2), 50..51 -> out (+bias, float4),
//    52..53 -> ydot stride 32 (8B dwordx2).
// ---------------------------------------------------------------------------
__global__ __launch_bounds__(256) void k1_xw(
    const float* __restrict__ x, const unsigned short* __restrict__ wbf,
    const int* __restrict__ ei, const float* __restrict__ bias,
    int* __restrict__ deg, unsigned short* __restrict__ rank,
    unsigned short* __restrict__ xw, float* __restrict__ out,
    unsigned short* __restrict__ ydot) {
  int tid = threadIdx.x;
  int b = blockIdx.x;

  int e = b * 256 + tid;
  int rk = atomicAdd(&deg[ei[e]], 1);

  int wave = tid >> 6, lane = tid & 63;
  int quad = lane >> 4, c16 = lane & 15;
  int n0 = b * 16;
  int node = n0 + c16;
  const float* xp = x + (size_t)node * 32 + quad * 8;
  float4 a0 = *reinterpret_cast<const float4*>(xp);
  float4 a1 = *reinterpret_cast<const float4*>(xp + 4);
  short8 xf;   // B-fragment: B[k=quad*8+j][n=c16] = x[node][k]
  xf[0] = (short)f32_to_bf16(a0.x); xf[1] = (short)f32_to_bf16(a0.y);
  xf[2] = (short)f32_to_bf16(a0.z); xf[3] = (short)f32_to_bf16(a0.w);
  xf[4] = (short)f32_to_bf16(a1.x); xf[5] = (short)f32_to_bf16(a1.y);
  xf[6] = (short)f32_to_bf16(a1.z); xf[7] = (short)f32_to_bf16(a1.w);

  unsigned short* xwrow = xw + (size_t)node * 800;
  for (int t = wave; t < 54; t += 4) {
    // A-fragment: A[m=c16][k=quad*8+j] = W_tile[k][f0+c16] (same storage as B)
    short8 wf = *reinterpret_cast<const short8*>(wbf + ((t * 4 + quad) * 16 + c16) * 8);
    float4v acc = {0.f, 0.f, 0.f, 0.f};
    acc = __builtin_amdgcn_mfma_f32_16x16x32_bf16(wf, xf, acc, 0, 0, 0);
    // lane holds D[f = half*16 + quad*4 + r][node = c16]
    if (t < 50) {
      int col = (t >> 1) * 32 + (t & 1) * 16 + quad * 4;
      uint2 pk;
      pk.x = pack2bf16(acc[0], acc[1]);
      pk.y = pack2bf16(acc[2], acc[3]);
      *reinterpret_cast<uint2*>(xwrow + col) = pk;
    } else if (t < 52) {
      int f0 = (t - 50) * 16 + quad * 4;
      float4 o;
      o.x = acc[0] + bias[f0];
      o.y = acc[1] + bias[f0 + 1];
      o.z = acc[2] + bias[f0 + 2];
      o.w = acc[3] + bias[f0 + 3];
      *reinterpret_cast<float4*>(out + (size_t)node * 32 + f0) = o;
    } else {
      int cg0 = (t - 52) * 16 + quad * 4;   // 0..28; cols >=26 are zeros
      uint2 pk;
      pk.x = pack2bf16(acc[0], acc[1]);
      pk.y = pack2bf16(acc[2], acc[3]);
      *reinterpret_cast<uint2*>(ydot + (size_t)node * 32 + cg0) = pk;
    }
  }
  rank[e] = (unsigned short)rk;
}

// ---------------------------------------------------------------------------
// K_scan: single-kernel decoupled-lookback exclusive scan (391 tiles x 256).
// ---------------------------------------------------------------------------
__global__ __launch_bounds__(256) void k_scan(
    const int* __restrict__ deg, int* __restrict__ offs,
    int* __restrict__ tilectr, unsigned long long* __restrict__ tilepack) {
  __shared__ int s[256];
  __shared__ int sh_tile, sh_excl;
  int tid = threadIdx.x;
  if (tid == 0) sh_tile = atomicAdd(tilectr, 1);
  __syncthreads();
  int tile = sh_tile;
  int i = tile * 256 + tid;
  int v = (i < N_NODES) ? deg[i] : 0;
  s[tid] = v;
  __syncthreads();
  for (int d = 1; d < 256; d <<= 1) {
    int t = (tid >= d) ? s[tid - d] : 0;
    __syncthreads();
    s[tid] += t;
    __syncthreads();
  }
  int incl = s[tid];
  int agg = s[255];
  if (tid == 0) {
    unsigned long long init = ((tile == 0) ? (2ull << 32) : (1ull << 32)) | (unsigned int)agg;
    __hip_atomic_store(&tilepack[tile], init, __ATOMIC_RELEASE, __HIP_MEMORY_SCOPE_AGENT);
    if (tile == 0) sh_excl = 0;
  }
  if (tile > 0 && tid < 64) {
    int excl = 0;
    int base = tile - 1;
    while (true) {
      int look = base - tid;
      unsigned long long pk;
      if (look >= 0) {
        do {
          pk = __hip_atomic_load(&tilepack[look], __ATOMIC_ACQUIRE, __HIP_MEMORY_SCOPE_AGENT);
        } while ((pk >> 32) == 0);
      } else {
        pk = (2ull << 32);
      }
      unsigned long long m2 = __ballot((pk >> 32) == 2);
      int lim = (m2 == 0ull) ? 64 : (__ffsll(m2) - 1);
      int val = (tid <= lim) ? (int)(unsigned int)pk : 0;
#pragma unroll
      for (int m = 1; m < 64; m <<= 1) val += __shfl_xor(val, m);
      excl += val;
      if (lim < 64) break;
      base -= 64;
    }
    if (tid == 0) {
      __hip_atomic_store(&tilepack[tile], (2ull << 32) | (unsigned int)(excl + agg),
                         __ATOMIC_RELEASE, __HIP_MEMORY_SCOPE_AGENT);
      sh_excl = excl;
    }
  }
  __syncthreads();
  if (i < N_NODES) offs[i] = sh_excl + incl - v;
  if (i == N_NODES - 1) offs[N_NODES] = N_EDGES;
}

// ---------------------------------------------------------------------------
// K_scatter: pos = offs[row] + rank[e] (no atomics). Full attention weight:
// alpha = rd + sum_s b_s*ydot[col][w_s]; ex = exp(leakyrelu(alpha)).
// Packet: x: col(17) | i0(3) | i1(3) | fr0q(8);  y: fr1q(8) | ex_bf16(hi16).
// ---------------------------------------------------------------------------
__global__ __launch_bounds__(256) void kscatter(
    const int* __restrict__ ei, const float* __restrict__ pseudo,
    const int* __restrict__ offs, const unsigned short* __restrict__ rank,
    const unsigned short* __restrict__ ydot, uint2* __restrict__ epack) {
  int e = blockIdx.x * 256 + threadIdx.x;   // 6250 blocks: exact cover
  int r = ei[e];
  int c = ei[N_EDGES + e];
  int pos = offs[r] + (int)rank[e];
  float p0 = pseudo[2 * e] * 4.f;
  float p1 = pseudo[2 * e + 1] * 4.f;
  float fl0 = floorf(p0), fl1 = floorf(p1);
  float fr0 = p0 - fl0, fr1 = p1 - fl1;
  int i0 = (int)fl0, i1 = (int)fl1;
  int j0p = min(i0 + 1, 4);
  int j1 = 5 * i1, j1p = 5 * min(i1 + 1, 4);
  int rb = c * 32;
  float y0 = bf16_to_f32(ydot[rb + i0 + j1]);
  float y1 = bf16_to_f32(ydot[rb + j0p + j1]);
  float y2 = bf16_to_f32(ydot[rb + i0 + j1p]);
  float y3 = bf16_to_f32(ydot[rb + j0p + j1p]);
  float rd = bf16_to_f32(ydot[(size_t)r * 32 + 25]);
  float fm0 = 1.f - fr0, fm1 = 1.f - fr1;
  float b0 = fm0 * fm1, b1 = fr0 * fm1, b2 = fm0 * fr1, b3 = fr0 * fr1;
  float alpha = rd + b0 * y0 + b1 * y1 + b2 * y2 + b3 * y3;
  alpha = fmaxf(alpha, 0.2f * alpha);   // leaky relu
  float ex = __expf(alpha);
  unsigned u = __float_as_uint(ex);
  unsigned exb = (u + 0x7fffu + ((u >> 16) & 1u)) & 0xffff0000u;  // bf16 RNE
  unsigned q0 = __float2uint_rn(fr0 * 255.f);
  unsigned q1 = __float2uint_rn(fr1 * 255.f);
  uint2 pk;
  pk.x = (unsigned)c | ((unsigned)i0 << 17) | ((unsigned)i1 << 20) | (q0 << 23);
  pk.y = exb | q1;
  epack[pos] = pk;
}

// ---------------------------------------------------------------------------
// K2: one wave per node; halves process alternate edges (lane=f_out).
// No cross-lane ops, no exp: 4 gathers + blend + 2 fma per edge; 4-deep unroll.
// ---------------------------------------------------------------------------
__device__ __forceinline__ void edge_step(uint2 pk, const unsigned short* __restrict__ xwf,
                                          float& acc, float& den) {
  int c  = (int)(pk.x & 0x1FFFF);
  int i0 = (int)((pk.x >> 17) & 7);
  int i1 = (int)((pk.x >> 20) & 7);
  float fr0 = (float)((pk.x >> 23) & 255u) * (1.f / 255.f);
  float fr1 = (float)(pk.y & 255u) * (1.f / 255.f);
  float ex = __uint_as_float(pk.y & 0xffff0000u);
  int j0p = min(i0 + 1, 4);
  int j1 = 5 * i1, j1p = 5 * min(i1 + 1, 4);
  int base = c * 800;
  float g0 = bf16_to_f32(xwf[base + (i0 + j1) * 32]);
  float g1 = bf16_to_f32(xwf[base + (j0p + j1) * 32]);
  float g2 = bf16_to_f32(xwf[base + (i0 + j1p) * 32]);
  float g3 = bf16_to_f32(xwf[base + (j0p + j1p) * 32]);
  float fm0 = 1.f - fr0, fm1 = 1.f - fr1;
  float msg = fm1 * (fm0 * g0 + fr0 * g1) + fr1 * (fm0 * g2 + fr0 * g3);
  acc = fmaf(msg, ex, acc);
  den += ex;
}

__global__ __launch_bounds__(256) void k2_csr(
    const int* __restrict__ offs, const uint2* __restrict__ epack,
    const unsigned short* __restrict__ xw, float* __restrict__ out) {
  int tid = threadIdx.x;
  int wave = tid >> 6, lane = tid & 63;
  int node = blockIdx.x * 4 + wave;
  if (node >= N_NODES) return;
  int f = lane & 31, half = lane >> 5;
  int s0 = offs[node], s1 = offs[node + 1];
  const unsigned short* xwf = xw + f;
  float acc = 0.f, den = 0.f;
  int i = s0 + half;

  for (; i + 6 < s1; i += 8) {
    uint2 p0 = epack[i];
    uint2 p1 = epack[i + 2];
    uint2 p2 = epack[i + 4];
    uint2 p3 = epack[i + 6];
    edge_step(p0, xwf, acc, den);
    edge_step(p1, xwf, acc, den);
    edge_step(p2, xwf, acc, den);
    edge_step(p3, xwf, acc, den);
  }
  for (; i < s1; i += 2) edge_step(epack[i], xwf, acc, den);

  acc += __shfl_xor(acc, 32);
  den += __shfl_xor(den, 32);
  if (half == 0) out[node * 32 + f] += acc / (den + 1e-16f);
}

extern "C" void kernel_launch(void* const* d_in, const int* in_sizes, int n_in,
                              void* d_out, int out_size, void* d_ws, size_t ws_size,
                              hipStream_t stream) {
  const float* x      = (const float*)d_in[0];
  const int*   ei     = (const int*)d_in[1];
  const float* pseudo = (const float*)d_in[2];
  const float* weight = (const float*)d_in[3];
  const float* root_w = (const float*)d_in[4];
  const float* att_w  = (const float*)d_in[5];
  const float* bias   = (const float*)d_in[6];
  float* out = (float*)d_out;

  char* ws = (char*)d_ws;
  unsigned short* xw   = (unsigned short*)ws;                 // 160,000,000 B
  unsigned short* wbf  = (unsigned short*)(ws + 160000000);   //     57,344 B (54 tiles)
  int* deg             = (int*)(ws + 160057344);              //    400,000 B
  int* offs            = (int*)(ws + 160457344);              //    400,016 B
  unsigned long long* tilepack = (unsigned long long*)(ws + 160857360); // 3,128 B
  int* tilectr         = (int*)(ws + 160860488);              //          8 B
  unsigned short* rank = (unsigned short*)(ws + 160860496);   //  3,200,000 B
  unsigned short* ydot = (unsigned short*)(ws + 164060496);   //  6,400,000 B (32/node)
  uint2* epack         = (uint2*)(ws + 170460496);            // 12,800,000 B -> 183.3 MB

  hipLaunchKernelGGL(k_zero, dim3(NBLK_SCAN), dim3(256), 0, stream,
                     weight, root_w, att_w, deg, wbf, tilepack, tilectr);
  hipLaunchKernelGGL(k1_xw, dim3(6250), dim3(256), 0, stream,
                     x, wbf, ei, bias, deg, rank, xw, out, ydot);
  hipLaunchKernelGGL(k_scan, dim3(NBLK_SCAN), dim3(256), 0, stream,
                     deg, offs, tilectr, tilepack);
  hipLaunchKernelGGL(kscatter, dim3(6250), dim3(256), 0, stream,
                     ei, pseudo, offs, rank, ydot, epack);
  hipLaunchKernelGGL(k2_csr, dim3(25000), dim3(256), 0, stream,
                     offs, epack, xw, out);
}

// Round 9
// 361.339 us; speedup vs baseline: 1.0558x; 1.0558x over previous
//
#include <hip/hip_runtime.h>
#include <stdint.h>

#define N_NODES 100000
#define N_EDGES 1600000
#define NBLK_SCAN 391   // ceil(N_NODES/256)

typedef __attribute__((ext_vector_type(8))) short short8;
typedef __attribute__((ext_vector_type(4))) float float4v;

__device__ __forceinline__ unsigned short f32_to_bf16(float f) {
  uint32_t u = __float_as_uint(f);
  u += 0x7fffu + ((u >> 16) & 1u);   // RNE
  return (unsigned short)(u >> 16);
}
__device__ __forceinline__ float bf16_to_f32(unsigned short h) {
  return __uint_as_float(((uint32_t)h) << 16);
}
__device__ __forceinline__ unsigned pack2bf16(float a, float b) {
  return (unsigned)f32_to_bf16(a) | ((unsigned)f32_to_bf16(b) << 16);
}

// ---------------------------------------------------------------------------
// K_zero: deg=0, tilepack=0, tilectr=0; swizzle weight (tiles 0..49), root_w
// (tiles 50..51), and M[26][32] (tiles 52..53, zero-padded) into fragment
// order wbf[((t*4+q)*16+c)*8+j] = W[kk=q*8+j][col=c].
// M[k][fin] = sum_fo W_k[fin][fo]*att_w[32+fo] (k<25); M[25][fin] =
// sum_fo root_w[fin][fo]*att_w[fo].
// ---------------------------------------------------------------------------
__global__ __launch_bounds__(256) void k_zero(
    const float* __restrict__ weight, const float* __restrict__ root_w,
    const float* __restrict__ att_w,
    int* __restrict__ deg, unsigned short* __restrict__ wbf,
    unsigned long long* __restrict__ tilepack, int* __restrict__ tilectr) {
  int tid = threadIdx.x;
  int b = blockIdx.x;
  int i = b * 256 + tid;
  if (i < N_NODES) deg[i] = 0;
  if (i < NBLK_SCAN) tilepack[i] = 0ull;
  if (i == 0) *tilectr = 0;
  if (b < 100) {            // 25600 weight elements -> tiles 0..49
    int e = i;
    int km = e >> 10;
    int rem = e & 1023;
    int kk = rem >> 5;
    int fo = rem & 31;
    int t = km * 2 + (fo >> 4);
    int c = fo & 15;
    int q = kk >> 3, j = kk & 7;
    wbf[((t * 4 + q) * 16 + c) * 8 + j] = f32_to_bf16(weight[e]);
  } else if (b == 100) {    // 1024 root_w elements -> tiles 50,51
    for (int idx = tid; idx < 1024; idx += 256) {
      int kk = idx >> 5;
      int fo = idx & 31;
      int t = 50 + (fo >> 4);
      int c = fo & 15;
      int q = kk >> 3, j = kk & 7;
      wbf[((t * 4 + q) * 16 + c) * 8 + j] = f32_to_bf16(root_w[idx]);
    }
  } else if (b == 101) {    // M tiles 52,53 (cols 26..31 zero)
    for (int idx = tid; idx < 1024; idx += 256) {
      int cg = idx >> 5;    // 0..31
      int kk = idx & 31;    // fin
      float s = 0.f;
      if (cg < 25) {
        const float* wp = weight + (cg * 32 + kk) * 32;
#pragma unroll
        for (int fo = 0; fo < 32; fo++) s += wp[fo] * att_w[32 + fo];
      } else if (cg == 25) {
        const float* rp = root_w + kk * 32;
#pragma unroll
        for (int fo = 0; fo < 32; fo++) s += rp[fo] * att_w[fo];
      }
      int t = 52 + (cg >> 4);
      int c = cg & 15;
      int q = kk >> 3, j = kk & 7;
      wbf[((t * 4 + q) * 16 + c) * 8 + j] = f32_to_bf16(s);
    }
  }
}

// ---------------------------------------------------------------------------
// K1 (6250 blocks, 16 nodes each; 6250*256 == N_EDGES exactly):
//  - hist: rank[e] = atomicAdd(&deg[ei[e]],1)
//  - transposed MFMA D[f,node] (lane = 4 consecutive f of one node):
//    xw tiles -> ONE ds_write_b64 per tile into ot[node][col] (stride 808,
//    2-way conflicts only), then fully-coalesced uint4 copy-out;
//    out tiles 50,51 (+bias) and ydot tiles 52,53 stored direct (small).
// ---------------------------------------------------------------------------
__global__ __launch_bounds__(256) void k1_xw(
    const float* __restrict__ x, const unsigned short* __restrict__ wbf,
    const int* __restrict__ ei, const float* __restrict__ bias,
    int* __restrict__ deg, unsigned short* __restrict__ rank,
    unsigned short* __restrict__ xw, float* __restrict__ out,
    unsigned short* __restrict__ ydot) {
  __shared__ __align__(16) unsigned short ot[16 * 808];
  int tid = threadIdx.x;
  int b = blockIdx.x;

  int e = b * 256 + tid;
  int rk = atomicAdd(&deg[ei[e]], 1);

  int wave = tid >> 6, lane = tid & 63;
  int quad = lane >> 4, c16 = lane & 15;
  int n0 = b * 16;
  int node = n0 + c16;
  const float* xp = x + (size_t)node * 32 + quad * 8;
  float4 a0 = *reinterpret_cast<const float4*>(xp);
  float4 a1 = *reinterpret_cast<const float4*>(xp + 4);
  short8 xf;   // B-fragment: B[k=quad*8+j][n=c16] = x[node][k]
  xf[0] = (short)f32_to_bf16(a0.x); xf[1] = (short)f32_to_bf16(a0.y);
  xf[2] = (short)f32_to_bf16(a0.z); xf[3] = (short)f32_to_bf16(a0.w);
  xf[4] = (short)f32_to_bf16(a1.x); xf[5] = (short)f32_to_bf16(a1.y);
  xf[6] = (short)f32_to_bf16(a1.z); xf[7] = (short)f32_to_bf16(a1.w);

  unsigned short* otn = ot + c16 * 808;
  for (int t = wave; t < 54; t += 4) {
    // A-fragment: A[m=c16][k=quad*8+j] = W_tile[k][f0+c16] (same storage as B)
    short8 wf = *reinterpret_cast<const short8*>(wbf + ((t * 4 + quad) * 16 + c16) * 8);
    float4v acc = {0.f, 0.f, 0.f, 0.f};
    acc = __builtin_amdgcn_mfma_f32_16x16x32_bf16(wf, xf, acc, 0, 0, 0);
    // lane holds D[f = quad*4 + r][node = c16] for tile t
    if (t < 50) {
      int col = (t >> 1) * 32 + (t & 1) * 16 + quad * 4;
      uint2 pk;
      pk.x = pack2bf16(acc[0], acc[1]);
      pk.y = pack2bf16(acc[2], acc[3]);
      *reinterpret_cast<uint2*>(otn + col) = pk;           // ds_write_b64
    } else if (t < 52) {
      int f0 = (t - 50) * 16 + quad * 4;
      float4 o;
      o.x = acc[0] + bias[f0];
      o.y = acc[1] + bias[f0 + 1];
      o.z = acc[2] + bias[f0 + 2];
      o.w = acc[3] + bias[f0 + 3];
      *reinterpret_cast<float4*>(out + (size_t)node * 32 + f0) = o;
    } else {
      int cg0 = (t - 52) * 16 + quad * 4;   // cols >=26 are zeros (padded)
      uint2 pk;
      pk.x = pack2bf16(acc[0], acc[1]);
      pk.y = pack2bf16(acc[2], acc[3]);
      *reinterpret_cast<uint2*>(ydot + (size_t)node * 32 + cg0) = pk;
    }
  }
  __syncthreads();

  // coalesced copy-out: ot rows (101 uint4 stride) -> xw rows (100 uint4)
  const uint4* src = (const uint4*)ot;
  uint4* dst = (uint4*)(xw + (size_t)n0 * 800);
  for (int i = tid; i < 1600; i += 256) {
    int r = i / 100;
    int c = i - r * 100;
    dst[r * 100 + c] = src[r * 101 + c];
  }
  rank[e] = (unsigned short)rk;
}

// ---------------------------------------------------------------------------
// K_scan: single-kernel decoupled-lookback exclusive scan (391 tiles x 256).
// ---------------------------------------------------------------------------
__global__ __launch_bounds__(256) void k_scan(
    const int* __restrict__ deg, int* __restrict__ offs,
    int* __restrict__ tilectr, unsigned long long* __restrict__ tilepack) {
  __shared__ int s[256];
  __shared__ int sh_tile, sh_excl;
  int tid = threadIdx.x;
  if (tid == 0) sh_tile = atomicAdd(tilectr, 1);
  __syncthreads();
  int tile = sh_tile;
  int i = tile * 256 + tid;
  int v = (i < N_NODES) ? deg[i] : 0;
  s[tid] = v;
  __syncthreads();
  for (int d = 1; d < 256; d <<= 1) {
    int t = (tid >= d) ? s[tid - d] : 0;
    __syncthreads();
    s[tid] += t;
    __syncthreads();
  }
  int incl = s[tid];
  int agg = s[255];
  if (tid == 0) {
    unsigned long long init = ((tile == 0) ? (2ull << 32) : (1ull << 32)) | (unsigned int)agg;
    __hip_atomic_store(&tilepack[tile], init, __ATOMIC_RELEASE, __HIP_MEMORY_SCOPE_AGENT);
    if (tile == 0) sh_excl = 0;
  }
  if (tile > 0 && tid < 64) {
    int excl = 0;
    int base = tile - 1;
    while (true) {
      int look = base - tid;
      unsigned long long pk;
      if (look >= 0) {
        do {
          pk = __hip_atomic_load(&tilepack[look], __ATOMIC_ACQUIRE, __HIP_MEMORY_SCOPE_AGENT);
        } while ((pk >> 32) == 0);
      } else {
        pk = (2ull << 32);
      }
      unsigned long long m2 = __ballot((pk >> 32) == 2);
      int lim = (m2 == 0ull) ? 64 : (__ffsll(m2) - 1);
      int val = (tid <= lim) ? (int)(unsigned int)pk : 0;
#pragma unroll
      for (int m = 1; m < 64; m <<= 1) val += __shfl_xor(val, m);
      excl += val;
      if (lim < 64) break;
      base -= 64;
    }
    if (tid == 0) {
      __hip_atomic_store(&tilepack[tile], (2ull << 32) | (unsigned int)(excl + agg),
                         __ATOMIC_RELEASE, __HIP_MEMORY_SCOPE_AGENT);
      sh_excl = excl;
    }
  }
  __syncthreads();
  if (i < N_NODES) offs[i] = sh_excl + incl - v;
  if (i == N_NODES - 1) offs[N_NODES] = N_EDGES;
}

// ---------------------------------------------------------------------------
// K_scatter: pos = offs[row] + rank[e] (no atomics). Full attention weight:
// alpha = rd + sum_s b_s*ydot[col][w_s]; ex = exp(leakyrelu(alpha)).
// Packet: x: col(17) | i0(3) | i1(3) | fr0q(8);  y: fr1q(8) | ex_bf16(hi16).
// ---------------------------------------------------------------------------
__global__ __launch_bounds__(256) void kscatter(
    const int* __restrict__ ei, const float* __restrict__ pseudo,
    const int* __restrict__ offs, const unsigned short* __restrict__ rank,
    const unsigned short* __restrict__ ydot, uint2* __restrict__ epack) {
  int e = blockIdx.x * 256 + threadIdx.x;   // 6250 blocks: exact cover
  int r = ei[e];
  int c = ei[N_EDGES + e];
  int pos = offs[r] + (int)rank[e];
  float p0 = pseudo[2 * e] * 4.f;
  float p1 = pseudo[2 * e + 1] * 4.f;
  float fl0 = floorf(p0), fl1 = floorf(p1);
  float fr0 = p0 - fl0, fr1 = p1 - fl1;
  int i0 = (int)fl0, i1 = (int)fl1;
  int j0p = min(i0 + 1, 4);
  int j1 = 5 * i1, j1p = 5 * min(i1 + 1, 4);
  int rb = c * 32;
  float y0 = bf16_to_f32(ydot[rb + i0 + j1]);
  float y1 = bf16_to_f32(ydot[rb + j0p + j1]);
  float y2 = bf16_to_f32(ydot[rb + i0 + j1p]);
  float y3 = bf16_to_f32(ydot[rb + j0p + j1p]);
  float rd = bf16_to_f32(ydot[(size_t)r * 32 + 25]);
  float fm0 = 1.f - fr0, fm1 = 1.f - fr1;
  float b0 = fm0 * fm1, b1 = fr0 * fm1, b2 = fm0 * fr1, b3 = fr0 * fr1;
  float alpha = rd + b0 * y0 + b1 * y1 + b2 * y2 + b3 * y3;
  alpha = fmaxf(alpha, 0.2f * alpha);   // leaky relu
  float ex = __expf(alpha);
  unsigned u = __float_as_uint(ex);
  unsigned exb = (u + 0x7fffu + ((u >> 16) & 1u)) & 0xffff0000u;  // bf16 RNE
  unsigned q0 = __float2uint_rn(fr0 * 255.f);
  unsigned q1 = __float2uint_rn(fr1 * 255.f);
  uint2 pk;
  pk.x = (unsigned)c | ((unsigned)i0 << 17) | ((unsigned)i1 << 20) | (q0 << 23);
  pk.y = exb | q1;
  epack[pos] = pk;
}

// ---------------------------------------------------------------------------
// K2: one wave per node; halves process alternate edges (lane=f_out).
// No cross-lane ops, no exp: 4 gathers + blend + 2 fma per edge; 4-deep unroll.
// ---------------------------------------------------------------------------
__device__ __forceinline__ void edge_step(uint2 pk, const unsigned short* __restrict__ xwf,
                                          float& acc, float& den) {
  int c  = (int)(pk.x & 0x1FFFF);
  int i0 = (int)((pk.x >> 17) & 7);
  int i1 = (int)((pk.x >> 20) & 7);
  float fr0 = (float)((pk.x >> 23) & 255u) * (1.f / 255.f);
  float fr1 = (float)(pk.y & 255u) * (1.f / 255.f);
  float ex = __uint_as_float(pk.y & 0xffff0000u);
  int j0p = min(i0 + 1, 4);
  int j1 = 5 * i1, j1p = 5 * min(i1 + 1, 4);
  int base = c * 800;
  float g0 = bf16_to_f32(xwf[base + (i0 + j1) * 32]);
  float g1 = bf16_to_f32(xwf[base + (j0p + j1) * 32]);
  float g2 = bf16_to_f32(xwf[base + (i0 + j1p) * 32]);
  float g3 = bf16_to_f32(xwf[base + (j0p + j1p) * 32]);
  float fm0 = 1.f - fr0, fm1 = 1.f - fr1;
  float msg = fm1 * (fm0 * g0 + fr0 * g1) + fr1 * (fm0 * g2 + fr0 * g3);
  acc = fmaf(msg, ex, acc);
  den += ex;
}

__global__ __launch_bounds__(256) void k2_csr(
    const int* __restrict__ offs, const uint2* __restrict__ epack,
    const unsigned short* __restrict__ xw, float* __restrict__ out) {
  int tid = threadIdx.x;
  int wave = tid >> 6, lane = tid & 63;
  int node = blockIdx.x * 4 + wave;
  if (node >= N_NODES) return;
  int f = lane & 31, half = lane >> 5;
  int s0 = offs[node], s1 = offs[node + 1];
  const unsigned short* xwf = xw + f;
  float acc = 0.f, den = 0.f;
  int i = s0 + half;

  for (; i + 6 < s1; i += 8) {
    uint2 p0 = epack[i];
    uint2 p1 = epack[i + 2];
    uint2 p2 = epack[i + 4];
    uint2 p3 = epack[i + 6];
    edge_step(p0, xwf, acc, den);
    edge_step(p1, xwf, acc, den);
    edge_step(p2, xwf, acc, den);
    edge_step(p3, xwf, acc, den);
  }
  for (; i < s1; i += 2) edge_step(epack[i], xwf, acc, den);

  acc += __shfl_xor(acc, 32);
  den += __shfl_xor(den, 32);
  if (half == 0) out[node * 32 + f] += acc / (den + 1e-16f);
}

extern "C" void kernel_launch(void* const* d_in, const int* in_sizes, int n_in,
                              void* d_out, int out_size, void* d_ws, size_t ws_size,
                              hipStream_t stream) {
  const float* x      = (const float*)d_in[0];
  const int*   ei     = (const int*)d_in[1];
  const float* pseudo = (const float*)d_in[2];
  const float* weight = (const float*)d_in[3];
  const float* root_w = (const float*)d_in[4];
  const float* att_w  = (const float*)d_in[5];
  const float* bias   = (const float*)d_in[6];
  float* out = (float*)d_out;

  char* ws = (char*)d_ws;
  unsigned short* xw   = (unsigned short*)ws;                 // 160,000,000 B
  unsigned short* wbf  = (unsigned short*)(ws + 160000000);   //     57,344 B (54 tiles)
  int* deg             = (int*)(ws + 160057344);              //    400,000 B
  int* offs            = (int*)(ws + 160457344);              //    400,016 B
  unsigned long long* tilepack = (unsigned long long*)(ws + 160857360); // 3,128 B
  int* tilectr         = (int*)(ws + 160860488);              //          8 B
  unsigned short* rank = (unsigned short*)(ws + 160860496);   //  3,200,000 B
  unsigned short* ydot = (unsigned short*)(ws + 164060496);   //  6,400,000 B (32/node)
  uint2* epack         = (uint2*)(ws + 170460496);            // 12,800,000 B -> 183.3 MB

  hipLaunchKernelGGL(k_zero, dim3(NBLK_SCAN), dim3(256), 0, stream,
                     weight, root_w, att_w, deg, wbf, tilepack, tilectr);
  hipLaunchKernelGGL(k1_xw, dim3(6250), dim3(256), 0, stream,
                     x, wbf, ei, bias, deg, rank, xw, out, ydot);
  hipLaunchKernelGGL(k_scan, dim3(NBLK_SCAN), dim3(256), 0, stream,
                     deg, offs, tilectr, tilepack);
  hipLaunchKernelGGL(kscatter, dim3(6250), dim3(256), 0, stream,
                     ei, pseudo, offs, rank, ydot, epack);
  hipLaunchKernelGGL(k2_csr, dim3(25000), dim3(256), 0, stream,
                     offs, epack, xw, out);
}

// Round 10
// 353.612 us; speedup vs baseline: 1.0789x; 1.0219x over previous
//
#include <hip/hip_runtime.h>
#include <stdint.h>

#define N_NODES 100000
#define N_EDGES 1600000
#define NBLK_SCAN 391   // ceil(N_NODES/256)

typedef __attribute__((ext_vector_type(8))) short short8;
typedef __attribute__((ext_vector_type(4))) float float4v;

__device__ __forceinline__ unsigned short f32_to_bf16(float f) {
  uint32_t u = __float_as_uint(f);
  u += 0x7fffu + ((u >> 16) & 1u);   // RNE
  return (unsigned short)(u >> 16);
}
__device__ __forceinline__ float bf16_to_f32(unsigned short h) {
  return __uint_as_float(((uint32_t)h) << 16);
}
__device__ __forceinline__ unsigned pack2bf16(float a, float b) {
  return (unsigned)f32_to_bf16(a) | ((unsigned)f32_to_bf16(b) << 16);
}
__device__ __forceinline__ unsigned bf16hi(float v) {   // RNE bf16 kept in high 16
  unsigned u = __float_as_uint(v);
  return (u + 0x7fffu + ((u >> 16) & 1u)) & 0xffff0000u;
}
__device__ __forceinline__ void q2(unsigned u, float inv, int& a, int& b) {
  float lo = __uint_as_float(u << 16);
  float hi = __uint_as_float(u & 0xffff0000u);
  a = __float2int_rn(lo * inv);
  b = __float2int_rn(hi * inv);
}

// ---------------------------------------------------------------------------
// K_zero: deg=0, tilepack=0, tilectr=0; swizzle weight (tiles 0..49), root_w
// (tiles 50..51), and M[26][32] (tiles 52..53, zero-padded) into fragment
// order wbf[((t*4+q)*16+c)*8+j] = W[kk=q*8+j][col=c].
// ---------------------------------------------------------------------------
__global__ __launch_bounds__(256) void k_zero(
    const float* __restrict__ weight, const float* __restrict__ root_w,
    const float* __restrict__ att_w,
    int* __restrict__ deg, unsigned short* __restrict__ wbf,
    unsigned long long* __restrict__ tilepack, int* __restrict__ tilectr) {
  int tid = threadIdx.x;
  int b = blockIdx.x;
  int i = b * 256 + tid;
  if (i < N_NODES) deg[i] = 0;
  if (i < NBLK_SCAN) tilepack[i] = 0ull;
  if (i == 0) *tilectr = 0;
  if (b < 100) {            // 25600 weight elements -> tiles 0..49
    int e = i;
    int km = e >> 10;
    int rem = e & 1023;
    int kk = rem >> 5;
    int fo = rem & 31;
    int t = km * 2 + (fo >> 4);
    int c = fo & 15;
    int q = kk >> 3, j = kk & 7;
    wbf[((t * 4 + q) * 16 + c) * 8 + j] = f32_to_bf16(weight[e]);
  } else if (b == 100) {    // 1024 root_w elements -> tiles 50,51
    for (int idx = tid; idx < 1024; idx += 256) {
      int kk = idx >> 5;
      int fo = idx & 31;
      int t = 50 + (fo >> 4);
      int c = fo & 15;
      int q = kk >> 3, j = kk & 7;
      wbf[((t * 4 + q) * 16 + c) * 8 + j] = f32_to_bf16(root_w[idx]);
    }
  } else if (b == 101) {    // M tiles 52,53 (cols 26..31 zero)
    for (int idx = tid; idx < 1024; idx += 256) {
      int cg = idx >> 5;    // 0..31
      int kk = idx & 31;    // fin
      float s = 0.f;
      if (cg < 25) {
        const float* wp = weight + (cg * 32 + kk) * 32;
#pragma unroll
        for (int fo = 0; fo < 32; fo++) s += wp[fo] * att_w[32 + fo];
      } else if (cg == 25) {
        const float* rp = root_w + kk * 32;
#pragma unroll
        for (int fo = 0; fo < 32; fo++) s += rp[fo] * att_w[fo];
      }
      int t = 52 + (cg >> 4);
      int c = cg & 15;
      int q = kk >> 3, j = kk & 7;
      wbf[((t * 4 + q) * 16 + c) * 8 + j] = f32_to_bf16(s);
    }
  }
}

// ---------------------------------------------------------------------------
// K1 (6250 blocks, 16 nodes each; 6250*256 == N_EDGES exactly):
//  - hist: rank[e] = atomicAdd(&deg[ei[e]],1)
//  - transposed MFMA D[f,node]; xw tiles -> LDS (stride 808, b64 writes);
//    out tiles 50,51 (+bias) and ydot tiles 52,53 stored direct.
//  - epilogue: per-node absmax from LDS tile -> int8 quantize -> coalesced
//    8B stores to xq (80 MB instead of 160); scale[n] = s/127.
// ---------------------------------------------------------------------------
__global__ __launch_bounds__(256) void k1_xw(
    const float* __restrict__ x, const unsigned short* __restrict__ wbf,
    const int* __restrict__ ei, const float* __restrict__ bias,
    int* __restrict__ deg, unsigned short* __restrict__ rank,
    int8_t* __restrict__ xq, float* __restrict__ scale,
    float* __restrict__ out, unsigned short* __restrict__ ydot) {
  __shared__ __align__(16) unsigned short ot[16 * 808];
  __shared__ float sinv[16];
  int tid = threadIdx.x;
  int b = blockIdx.x;

  int e = b * 256 + tid;
  int rk = atomicAdd(&deg[ei[e]], 1);

  int wave = tid >> 6, lane = tid & 63;
  int quad = lane >> 4, c16 = lane & 15;
  int n0 = b * 16;
  int node = n0 + c16;
  const float* xp = x + (size_t)node * 32 + quad * 8;
  float4 a0 = *reinterpret_cast<const float4*>(xp);
  float4 a1 = *reinterpret_cast<const float4*>(xp + 4);
  short8 xf;   // B-fragment: B[k=quad*8+j][n=c16] = x[node][k]
  xf[0] = (short)f32_to_bf16(a0.x); xf[1] = (short)f32_to_bf16(a0.y);
  xf[2] = (short)f32_to_bf16(a0.z); xf[3] = (short)f32_to_bf16(a0.w);
  xf[4] = (short)f32_to_bf16(a1.x); xf[5] = (short)f32_to_bf16(a1.y);
  xf[6] = (short)f32_to_bf16(a1.z); xf[7] = (short)f32_to_bf16(a1.w);

  unsigned short* otn = ot + c16 * 808;
  for (int t = wave; t < 54; t += 4) {
    short8 wf = *reinterpret_cast<const short8*>(wbf + ((t * 4 + quad) * 16 + c16) * 8);
    float4v acc = {0.f, 0.f, 0.f, 0.f};
    acc = __builtin_amdgcn_mfma_f32_16x16x32_bf16(wf, xf, acc, 0, 0, 0);
    // lane holds D[f = quad*4 + r][node = c16] for tile t
    if (t < 50) {
      int col = (t >> 1) * 32 + (t & 1) * 16 + quad * 4;
      uint2 pk;
      pk.x = pack2bf16(acc[0], acc[1]);
      pk.y = pack2bf16(acc[2], acc[3]);
      *reinterpret_cast<uint2*>(otn + col) = pk;           // ds_write_b64
    } else if (t < 52) {
      int f0 = (t - 50) * 16 + quad * 4;
      float4 o;
      o.x = acc[0] + bias[f0];
      o.y = acc[1] + bias[f0 + 1];
      o.z = acc[2] + bias[f0 + 2];
      o.w = acc[3] + bias[f0 + 3];
      *reinterpret_cast<float4*>(out + (size_t)node * 32 + f0) = o;
    } else {
      int cg0 = (t - 52) * 16 + quad * 4;   // cols >=26 are zeros (padded)
      uint2 pk;
      pk.x = pack2bf16(acc[0], acc[1]);
      pk.y = pack2bf16(acc[2], acc[3]);
      *reinterpret_cast<uint2*>(ydot + (size_t)node * 32 + cg0) = pk;
    }
  }
  __syncthreads();

  // per-node absmax (16 threads/node, same wave, width-16 shuffle reduce)
  int nn = tid >> 4, part = tid & 15;
  const uint4* rowp = (const uint4*)(ot + nn * 808);   // row stride 1616B, 16B-aligned
  unsigned mx = 0;
  for (int j = part; j < 100; j += 16) {
    uint4 v = rowp[j];
    unsigned a;
    a = v.x & 0x7fff7fffu; mx = max(mx, max(a & 0xffffu, a >> 16));
    a = v.y & 0x7fff7fffu; mx = max(mx, max(a & 0xffffu, a >> 16));
    a = v.z & 0x7fff7fffu; mx = max(mx, max(a & 0xffffu, a >> 16));
    a = v.w & 0x7fff7fffu; mx = max(mx, max(a & 0xffffu, a >> 16));
  }
#pragma unroll
  for (int m = 1; m < 16; m <<= 1) mx = max(mx, (unsigned)__shfl_xor((int)mx, m));
  float s = bf16_to_f32((unsigned short)mx);
  float inv = (s > 0.f) ? 127.f / s : 0.f;
  if (part == 0) {
    sinv[nn] = inv;
    scale[n0 + nn] = s * (1.f / 127.f);
  }
  __syncthreads();

  // quantize + coalesced copy-out: 1600 chunks of 8 bf16 -> 8 int8
  for (int i = tid; i < 1600; i += 256) {
    int r = i / 100;
    int c = i - r * 100;
    uint4 v = ((const uint4*)ot)[r * 101 + c];
    float iv = sinv[r];
    int b0, b1, b2, b3, b4, b5, b6, b7;
    q2(v.x, iv, b0, b1); q2(v.y, iv, b2, b3);
    q2(v.z, iv, b4, b5); q2(v.w, iv, b6, b7);
    uint2 o;
    o.x = (unsigned)(b0 & 255) | ((unsigned)(b1 & 255) << 8) |
          ((unsigned)(b2 & 255) << 16) | ((unsigned)(b3 & 255) << 24);
    o.y = (unsigned)(b4 & 255) | ((unsigned)(b5 & 255) << 8) |
          ((unsigned)(b6 & 255) << 16) | ((unsigned)(b7 & 255) << 24);
    *reinterpret_cast<uint2*>(xq + (size_t)(n0 + r) * 800 + c * 8) = o;
  }
  rank[e] = (unsigned short)rk;
}

// ---------------------------------------------------------------------------
// K_scan: single-kernel decoupled-lookback exclusive scan (391 tiles x 256).
// ---------------------------------------------------------------------------
__global__ __launch_bounds__(256) void k_scan(
    const int* __restrict__ deg, int* __restrict__ offs,
    int* __restrict__ tilectr, unsigned long long* __restrict__ tilepack) {
  __shared__ int s[256];
  __shared__ int sh_tile, sh_excl;
  int tid = threadIdx.x;
  if (tid == 0) sh_tile = atomicAdd(tilectr, 1);
  __syncthreads();
  int tile = sh_tile;
  int i = tile * 256 + tid;
  int v = (i < N_NODES) ? deg[i] : 0;
  s[tid] = v;
  __syncthreads();
  for (int d = 1; d < 256; d <<= 1) {
    int t = (tid >= d) ? s[tid - d] : 0;
    __syncthreads();
    s[tid] += t;
    __syncthreads();
  }
  int incl = s[tid];
  int agg = s[255];
  if (tid == 0) {
    unsigned long long init = ((tile == 0) ? (2ull << 32) : (1ull << 32)) | (unsigned int)agg;
    __hip_atomic_store(&tilepack[tile], init, __ATOMIC_RELEASE, __HIP_MEMORY_SCOPE_AGENT);
    if (tile == 0) sh_excl = 0;
  }
  if (tile > 0 && tid < 64) {
    int excl = 0;
    int base = tile - 1;
    while (true) {
      int look = base - tid;
      unsigned long long pk;
      if (look >= 0) {
        do {
          pk = __hip_atomic_load(&tilepack[look], __ATOMIC_ACQUIRE, __HIP_MEMORY_SCOPE_AGENT);
        } while ((pk >> 32) == 0);
      } else {
        pk = (2ull << 32);
      }
      unsigned long long m2 = __ballot((pk >> 32) == 2);
      int lim = (m2 == 0ull) ? 64 : (__ffsll(m2) - 1);
      int val = (tid <= lim) ? (int)(unsigned int)pk : 0;
#pragma unroll
      for (int m = 1; m < 64; m <<= 1) val += __shfl_xor(val, m);
      excl += val;
      if (lim < 64) break;
      base -= 64;
    }
    if (tid == 0) {
      __hip_atomic_store(&tilepack[tile], (2ull << 32) | (unsigned int)(excl + agg),
                         __ATOMIC_RELEASE, __HIP_MEMORY_SCOPE_AGENT);
      sh_excl = excl;
    }
  }
  __syncthreads();
  if (i < N_NODES) offs[i] = sh_excl + incl - v;
  if (i == N_NODES - 1) offs[N_NODES] = N_EDGES;
}

// ---------------------------------------------------------------------------
// K_scatter: pos = offs[row] + rank[e] (no atomics). alpha from ydot (bf16),
// ex = exp(leakyrelu(alpha)); sex = (s_col/127)*ex folds the int8 scale.
// Packet (uint4): x = fr0q8 | fr1q8<<8 | d0flag<<16 | d1flag<<17
//                 y = ex bf16 (hi16);  z = sex bf16 (hi16)
//                 w = byte-base = col*800 + (i0+5*i1)*32
// ---------------------------------------------------------------------------
__global__ __launch_bounds__(256) void kscatter(
    const int* __restrict__ ei, const float* __restrict__ pseudo,
    const int* __restrict__ offs, const unsigned short* __restrict__ rank,
    const unsigned short* __restrict__ ydot, const float* __restrict__ scale,
    uint4* __restrict__ epack) {
  int e = blockIdx.x * 256 + threadIdx.x;   // 6250 blocks: exact cover
  int r = ei[e];
  int c = ei[N_EDGES + e];
  int pos = offs[r] + (int)rank[e];
  float p0 = pseudo[2 * e] * 4.f;
  float p1 = pseudo[2 * e + 1] * 4.f;
  float fl0 = floorf(p0), fl1 = floorf(p1);
  float fr0 = p0 - fl0, fr1 = p1 - fl1;
  int i0 = (int)fl0, i1 = (int)fl1;
  int j0p = min(i0 + 1, 4);
  int j1 = 5 * i1, j1p = 5 * min(i1 + 1, 4);
  int rb = c * 32;
  float y0 = bf16_to_f32(ydot[rb + i0 + j1]);
  float y1 = bf16_to_f32(ydot[rb + j0p + j1]);
  float y2 = bf16_to_f32(ydot[rb + i0 + j1p]);
  float y3 = bf16_to_f32(ydot[rb + j0p + j1p]);
  float rd = bf16_to_f32(ydot[(size_t)r * 32 + 25]);
  float fm0 = 1.f - fr0, fm1 = 1.f - fr1;
  float b0 = fm0 * fm1, b1 = fr0 * fm1, b2 = fm0 * fr1, b3 = fr0 * fr1;
  float alpha = rd + b0 * y0 + b1 * y1 + b2 * y2 + b3 * y3;
  alpha = fmaxf(alpha, 0.2f * alpha);   // leaky relu
  float ex = __expf(alpha);
  float sex = scale[c] * ex;
  unsigned q0 = __float2uint_rn(fr0 * 255.f);
  unsigned q1 = __float2uint_rn(fr1 * 255.f);
  uint4 pk;
  pk.x = q0 | (q1 << 8) | ((i0 < 4 ? 1u : 0u) << 16) | ((i1 < 4 ? 1u : 0u) << 17);
  pk.y = bf16hi(ex);
  pk.z = bf16hi(sex);
  pk.w = (unsigned)c * 800u + (unsigned)(i0 + 5 * i1) * 32u;
  epack[pos] = pk;
}

// ---------------------------------------------------------------------------
// K2: one wave per node; halves process alternate edges (lane=f_out 0..31).
// Per edge: 4 int8 gathers (32B segments) + blend + 2 fma. No cross-lane ops,
// no exp, no address math beyond precomputed base + clamp offsets.
// ---------------------------------------------------------------------------
__device__ __forceinline__ void edge_step(uint4 pk, const int8_t* __restrict__ xqf,
                                          float& acc, float& den) {
  float fr0 = (float)(pk.x & 255u) * (1.f / 255.f);
  float fr1 = (float)((pk.x >> 8) & 255u) * (1.f / 255.f);
  int d0 = (pk.x & 0x10000u) ? 32 : 0;
  int d1 = (pk.x & 0x20000u) ? 160 : 0;
  float ex = __uint_as_float(pk.y);
  float sex = __uint_as_float(pk.z);
  const int8_t* p = xqf + pk.w;
  float g0 = (float)p[0];
  float g1 = (float)p[d0];
  float g2 = (float)p[d1];
  float g3 = (float)p[d0 + d1];
  float fm0 = 1.f - fr0, fm1 = 1.f - fr1;
  float msg = fm1 * (fm0 * g0 + fr0 * g1) + fr1 * (fm0 * g2 + fr0 * g3);
  acc = fmaf(msg, sex, acc);
  den += ex;
}

__global__ __launch_bounds__(256) void k2_csr(
    const int* __restrict__ offs, const uint4* __restrict__ epack,
    const int8_t* __restrict__ xq, float* __restrict__ out) {
  int tid = threadIdx.x;
  int wave = tid >> 6, lane = tid & 63;
  int node = blockIdx.x * 4 + wave;
  if (node >= N_NODES) return;
  int f = lane & 31, half = lane >> 5;
  int s0 = offs[node], s1 = offs[node + 1];
  const int8_t* xqf = xq + f;
  float acc = 0.f, den = 0.f;
  int i = s0 + half;

  for (; i + 6 < s1; i += 8) {
    uint4 p0 = epack[i];
    uint4 p1 = epack[i + 2];
    uint4 p2 = epack[i + 4];
    uint4 p3 = epack[i + 6];
    edge_step(p0, xqf, acc, den);
    edge_step(p1, xqf, acc, den);
    edge_step(p2, xqf, acc, den);
    edge_step(p3, xqf, acc, den);
  }
  for (; i < s1; i += 2) edge_step(epack[i], xqf, acc, den);

  acc += __shfl_xor(acc, 32);
  den += __shfl_xor(den, 32);
  if (half == 0) out[node * 32 + f] += acc / (den + 1e-16f);
}

extern "C" void kernel_launch(void* const* d_in, const int* in_sizes, int n_in,
                              void* d_out, int out_size, void* d_ws, size_t ws_size,
                              hipStream_t stream) {
  const float* x      = (const float*)d_in[0];
  const int*   ei     = (const int*)d_in[1];
  const float* pseudo = (const float*)d_in[2];
  const float* weight = (const float*)d_in[3];
  const float* root_w = (const float*)d_in[4];
  const float* att_w  = (const float*)d_in[5];
  const float* bias   = (const float*)d_in[6];
  float* out = (float*)d_out;

  char* ws = (char*)d_ws;
  int8_t* xq          = (int8_t*)ws;                          //  80,000,000 B
  float* scale        = (float*)(ws + 80000000);              //     400,000 B
  unsigned short* wbf = (unsigned short*)(ws + 80400000);     //      57,344 B
  int* deg            = (int*)(ws + 80457344);                //     400,000 B
  int* offs           = (int*)(ws + 80857344);                //     400,016 B
  unsigned long long* tilepack = (unsigned long long*)(ws + 81257360); // 3,128 B
  int* tilectr        = (int*)(ws + 81260488);                //           8 B
  unsigned short* rank = (unsigned short*)(ws + 81260496);    //   3,200,000 B
  unsigned short* ydot = (unsigned short*)(ws + 84460496);    //   6,400,000 B (32/node)
  uint4* epack        = (uint4*)(ws + 90860496);              //  25,600,000 B -> 116.5 MB

  hipLaunchKernelGGL(k_zero, dim3(NBLK_SCAN), dim3(256), 0, stream,
                     weight, root_w, att_w, deg, wbf, tilepack, tilectr);
  hipLaunchKernelGGL(k1_xw, dim3(6250), dim3(256), 0, stream,
                     x, wbf, ei, bias, deg, rank, xq, scale, out, ydot);
  hipLaunchKernelGGL(k_scan, dim3(NBLK_SCAN), dim3(256), 0, stream,
                     deg, offs, tilectr, tilepack);
  hipLaunchKernelGGL(kscatter, dim3(6250), dim3(256), 0, stream,
                     ei, pseudo, offs, rank, ydot, scale, epack);
  hipLaunchKernelGGL(k2_csr, dim3(25000), dim3(256), 0, stream,
                     offs, epack, xq, out);
}